// Round 7
// baseline (429.774 us; speedup 1.0000x reference)
//
#include <hip/hip_runtime.h>
#include <hip/hip_bf16.h>

// Problem constants
#define BB 8
#define TT 1024
#define CC 512
#define HH 8
#define EE 256            // head dim (= C/2)
#define MM (BB*TT)        // 8192 rows
#define HE (HH*EE)        // 2048

using short8 = __attribute__((ext_vector_type(8))) short;
using f32x16 = __attribute__((ext_vector_type(16))) float;
using uint2v = __attribute__((ext_vector_type(2))) unsigned int;

__device__ __forceinline__ float bf2f(unsigned short u) {
  union { float f; unsigned int i; } v; v.i = ((unsigned int)u) << 16; return v.f;
}
__device__ __forceinline__ unsigned short f2bf(float f) {
  union { float f; unsigned int i; } v; v.f = f;
  unsigned int r = v.i + 0x7FFFu + ((v.i >> 16) & 1u);  // RNE
  return (unsigned short)(r >> 16);
}
__device__ __forceinline__ unsigned int pk_bf16(float lo, float hi) {
  unsigned int r;
  asm("v_cvt_pk_bf16_f32 %0, %1, %2" : "=v"(r) : "v"(lo), "v"(hi));
  return r;
}
// async global->LDS, 16B per lane; LDS dest = uniform base + lane*16
__device__ __forceinline__ void gll16(const void* g, void* l) {
  __builtin_amdgcn_global_load_lds(
      (const __attribute__((address_space(1))) unsigned int*)g,
      (__attribute__((address_space(3))) unsigned int*)l, 16, 0, 0);
}

// softmax numerator (exp2, log2e pre-folded into q) + pack 16 P values into
// two PV A-fragments via v_cvt_pk_bf16_f32 + permlane32_swap
__device__ __forceinline__ void softmax_pack(const f32x16& sacc, float& lacc,
                                             short8& pa0, short8& pa1) {
  short8 pa[2];
#pragma unroll
  for (int ksl = 0; ksl < 2; ++ksl) {
    float p0 = __builtin_amdgcn_exp2f(sacc[8 * ksl + 0]);
    float p1 = __builtin_amdgcn_exp2f(sacc[8 * ksl + 1]);
    float p2 = __builtin_amdgcn_exp2f(sacc[8 * ksl + 2]);
    float p3 = __builtin_amdgcn_exp2f(sacc[8 * ksl + 3]);
    float p4 = __builtin_amdgcn_exp2f(sacc[8 * ksl + 4]);
    float p5 = __builtin_amdgcn_exp2f(sacc[8 * ksl + 5]);
    float p6 = __builtin_amdgcn_exp2f(sacc[8 * ksl + 6]);
    float p7 = __builtin_amdgcn_exp2f(sacc[8 * ksl + 7]);
    lacc += ((p0 + p1) + (p2 + p3)) + ((p4 + p5) + (p6 + p7));
    unsigned int a1 = pk_bf16(p0, p1), a2 = pk_bf16(p2, p3);
    unsigned int b1 = pk_bf16(p4, p5), b2 = pk_bf16(p6, p7);
    uint2v r1 = __builtin_amdgcn_permlane32_swap(a1, b1, false, false);
    uint2v r2 = __builtin_amdgcn_permlane32_swap(a2, b2, false, false);
    union { unsigned int u[4]; short8 v; } uu;
    uu.u[0] = r1[0]; uu.u[1] = r2[0]; uu.u[2] = r1[1]; uu.u[3] = r2[1];
    pa[ksl] = uu.v;
  }
  pa0 = pa[0]; pa1 = pa[1];
}

// ---------------------------------------------------------------------------
// Kernel 1: FUSED QKV projection (MFMA) + x1 passthrough copy.
//   (unchanged from R6)
// ---------------------------------------------------------------------------
#define FSTR 72
__global__ __launch_bounds__(512) void qkv_fused_kernel(const float* __restrict__ x,
                                                        const float* __restrict__ Wq,
                                                        const float* __restrict__ Wk,
                                                        const float* __restrict__ Wv,
                                                        unsigned short* __restrict__ outq,
                                                        unsigned short* __restrict__ outk,
                                                        unsigned short* __restrict__ outvt,
                                                        float* __restrict__ out) {
  __shared__ unsigned short smem[4 * 128 * FSTR];   // As, Bq, Bk, Bv  (73728 B)
  unsigned short* As = smem;
  unsigned short* Bs[3] = { smem + 128 * FSTR, smem + 2 * 128 * FSTR, smem + 3 * 128 * FSTR };

  const int tid = threadIdx.x;
  const int lane = tid & 63;
  const int wid = tid >> 6;
  const int wr = wid >> 2, wc = wid & 3;
  const int lo = lane & 31, hi = lane >> 5;

  // XCD swizzle: xcd = bid&7 owns m-tiles [xcd*8, xcd*8+8), mt-inner
  int bid = blockIdx.x;
  int r = bid >> 3;
  int mt = (bid & 7) * 8 + (r & 7);
  int nt = r >> 3;                      // 0..15
  const int m0 = mt * 128;
  const int n0 = nt * 128;

  const float* Wp[3] = { Wq, Wk, Wv };
  const float scl[3] = { 0.25f * 1.44269504089f, 0.25f, 1.0f };

  const int srow = tid >> 2;            // 0..127
  const int sc0 = (tid & 3) * 16;       // f32 col base (16 per thread)

  float4 ra[4], rb[3][4];
  f32x16 acc[3][2];
#pragma unroll
  for (int w = 0; w < 3; ++w)
#pragma unroll
    for (int mi = 0; mi < 2; ++mi)
#pragma unroll
      for (int q = 0; q < 16; ++q) acc[w][mi][q] = 0.f;

  // prologue loads (k0 = 0)
#pragma unroll
  for (int j = 0; j < 4; ++j)
    ra[j] = *reinterpret_cast<const float4*>(&x[(size_t)(m0 + srow) * CC + sc0 + 4 * j]);
#pragma unroll
  for (int w = 0; w < 3; ++w)
#pragma unroll
    for (int j = 0; j < 4; ++j)
      rb[w][j] = *reinterpret_cast<const float4*>(&Wp[w][(size_t)(n0 + srow) * EE + sc0 + 4 * j]);

  for (int t = 0; t < 4; ++t) {
    // cvt + ds_write current regs
    {
      union { unsigned int u[4]; short8 v; } p0, p1;
      p0.u[0] = pk_bf16(ra[0].x, ra[0].y); p0.u[1] = pk_bf16(ra[0].z, ra[0].w);
      p0.u[2] = pk_bf16(ra[1].x, ra[1].y); p0.u[3] = pk_bf16(ra[1].z, ra[1].w);
      p1.u[0] = pk_bf16(ra[2].x, ra[2].y); p1.u[1] = pk_bf16(ra[2].z, ra[2].w);
      p1.u[2] = pk_bf16(ra[3].x, ra[3].y); p1.u[3] = pk_bf16(ra[3].z, ra[3].w);
      *reinterpret_cast<short8*>(&As[srow * FSTR + sc0]) = p0.v;
      *reinterpret_cast<short8*>(&As[srow * FSTR + sc0 + 8]) = p1.v;
#pragma unroll
      for (int w = 0; w < 3; ++w) {
        union { unsigned int u[4]; short8 v; } q0, q1;
        q0.u[0] = pk_bf16(rb[w][0].x, rb[w][0].y); q0.u[1] = pk_bf16(rb[w][0].z, rb[w][0].w);
        q0.u[2] = pk_bf16(rb[w][1].x, rb[w][1].y); q0.u[3] = pk_bf16(rb[w][1].z, rb[w][1].w);
        q1.u[0] = pk_bf16(rb[w][2].x, rb[w][2].y); q1.u[1] = pk_bf16(rb[w][2].z, rb[w][2].w);
        q1.u[2] = pk_bf16(rb[w][3].x, rb[w][3].y); q1.u[3] = pk_bf16(rb[w][3].z, rb[w][3].w);
        *reinterpret_cast<short8*>(&Bs[w][srow * FSTR + sc0]) = q0.v;
        *reinterpret_cast<short8*>(&Bs[w][srow * FSTR + sc0 + 8]) = q1.v;
      }
    }
    // fused x1 copy: nt==0 blocks store the x-tile slice (still in ra)
    if (n0 == 0) {
      int k0 = t * 64;
#pragma unroll
      for (int j = 0; j < 4; ++j)
        *reinterpret_cast<float4*>(&out[(size_t)(m0 + srow) * CC + k0 + sc0 + 4 * j]) = ra[j];
    }
    asm volatile("s_waitcnt lgkmcnt(0)" ::: "memory");
    __builtin_amdgcn_s_barrier();
    __builtin_amdgcn_sched_barrier(0);

    if (t + 1 < 4) {
      int k0 = (t + 1) * 64;
#pragma unroll
      for (int j = 0; j < 4; ++j)
        ra[j] = *reinterpret_cast<const float4*>(&x[(size_t)(m0 + srow) * CC + k0 + sc0 + 4 * j]);
#pragma unroll
      for (int w = 0; w < 3; ++w)
#pragma unroll
        for (int j = 0; j < 4; ++j)
          rb[w][j] = *reinterpret_cast<const float4*>(&Wp[w][(size_t)(n0 + srow) * EE + k0 + sc0 + 4 * j]);
    }

    __builtin_amdgcn_s_setprio(1);
#pragma unroll
    for (int ks = 0; ks < 4; ++ks) {
      short8 af[2];
#pragma unroll
      for (int mi = 0; mi < 2; ++mi)
        af[mi] = *reinterpret_cast<const short8*>(&As[(64 * wr + 32 * mi + lo) * FSTR + ks * 16 + hi * 8]);
#pragma unroll
      for (int w = 0; w < 3; ++w) {
        short8 bf = *reinterpret_cast<const short8*>(&Bs[w][(32 * wc + lo) * FSTR + ks * 16 + hi * 8]);
#pragma unroll
        for (int mi = 0; mi < 2; ++mi)
          acc[w][mi] = __builtin_amdgcn_mfma_f32_32x32x16_bf16(af[mi], bf, acc[w][mi], 0, 0, 0);
      }
    }
    __builtin_amdgcn_s_setprio(0);
    __builtin_amdgcn_s_barrier();
    __builtin_amdgcn_sched_barrier(0);
  }

  // ---- epilogue: q, k direct coalesced stores
#pragma unroll
  for (int w = 0; w < 2; ++w) {
    unsigned short* op = (w == 0) ? outq : outk;
#pragma unroll
    for (int mi = 0; mi < 2; ++mi) {
#pragma unroll
      for (int q = 0; q < 16; ++q) {
        int rr = (q & 3) + 8 * (q >> 2) + 4 * hi;
        int m = m0 + 64 * wr + 32 * mi + rr;
        int n = n0 + 32 * wc + lo;
        op[(size_t)m * HE + n] = f2bf(acc[w][mi][q] * scl[w]);
      }
    }
  }

  // ---- V: LDS transpose then coalesced vt stores
  unsigned short* Tr = smem;            // [128 n][136] m-major rows
  __syncthreads();                      // everyone done with As/Bs
#pragma unroll
  for (int mi = 0; mi < 2; ++mi)
#pragma unroll
    for (int q = 0; q < 16; ++q) {
      int rr = (q & 3) + 8 * (q >> 2) + 4 * hi;
      Tr[(32 * wc + lo) * 136 + 64 * wr + 32 * mi + rr] = f2bf(acc[2][mi][q]);
    }
  __syncthreads();
  {
    const int b = m0 >> 10;
    const int t0m = m0 & 1023;
#pragma unroll
    for (int p = 0; p < 4; ++p) {
      int nr = p * 32 + (tid >> 4);
      int chunk = tid & 15;
      int n = n0 + nr;
      size_t drow = ((size_t)b * 8 + (n >> 8)) * 256 + (n & 255);
      *reinterpret_cast<short8*>(&outvt[drow * TT + t0m + chunk * 8]) =
          *reinterpret_cast<const short8*>(&Tr[nr * 136 + chunk * 8]);
    }
  }
}

// ---------------------------------------------------------------------------
// Kernel 2: MFMA attention, fat-wave variant.
//   256 thr = 4 waves; each wave owns 64 q-rows x 256 e (Oacc 256 VGPR,
//   1 wave/SIMD).  Block = 256 q-rows; grid = 256 = 1 block/CU.
//   Staged tile SBLK=64 (K[64][256] + Vt[256][64], double-buffered, 129KB),
//   computed as two 32-s subtiles.  Each K-frag / V-frag LDS read feeds TWO
//   MFMAs (q-subtiles 0,1) -> LDS read:MFMA = 1:2 (was 1:1).
//   global_load_lds staging, XOR-granule pre-swizzle on global source,
//   same XOR on read side (both-sides rule).  No setprio (1 wave/SIMD).
// ---------------------------------------------------------------------------
#define SBLK 64
__global__ __launch_bounds__(256, 1) void attn_kernel(const unsigned short* __restrict__ qg,
                                                      const unsigned short* __restrict__ kg,
                                                      const unsigned short* __restrict__ vtg,
                                                      unsigned short* __restrict__ og) {
  __shared__ char smem[132096];
  unsigned short* Kbuf = (unsigned short*)smem;              // 2 x [64][256]
  unsigned short* Vbuf = (unsigned short*)(smem + 65536);    // 2 x [256][64]
  float* lpart = (float*)(smem + 131072);                    // [256]

  const int tid = threadIdx.x;
  const int lane = tid & 63;
  const int wid = tid >> 6;           // 0..3: q 64-row subtile
  const int lo = lane & 31, hi = lane >> 5;

  // XCD-aware bijective swizzle: 4 t-tiles of each (b,h) stay on one XCD
  int logical = (blockIdx.x & 7) * 32 + (blockIdx.x >> 3);
  const int bh = logical >> 2;
  const int t0 = (logical & 3) * 256;
  const int b = bh >> 3, h = bh & 7;
  const size_t qkbase = (size_t)b * TT * HE + (size_t)h * EE;
  const size_t vtbase = (size_t)bh * EE * TT;
  const unsigned short* kg_base = kg + qkbase;
  const unsigned short* vt_base = vtg + vtbase;

  // hoist Q fragments (B-operand) for both q-subtiles: rows t0+64*wid+32*qs+lo
  short8 qf0[16], qf1[16];
  {
    const unsigned short* qrow0 = qg + qkbase + (size_t)(t0 + 64 * wid + lo) * HE + hi * 8;
    const unsigned short* qrow1 = qrow0 + (size_t)32 * HE;
#pragma unroll
    for (int ks = 0; ks < 16; ++ks) {
      qf0[ks] = *reinterpret_cast<const short8*>(qrow0 + ks * 16);
      qf1[ks] = *reinterpret_cast<const short8*>(qrow1 + ks * 16);
    }
  }

  f32x16 Oacc0[8], Oacc1[8];
#pragma unroll
  for (int et = 0; et < 8; ++et)
#pragma unroll
    for (int q = 0; q < 16; ++q) { Oacc0[et][q] = 0.f; Oacc1[et][q] = 0.f; }
  float lacc0 = 0.f, lacc1 = 0.f;

  // staging lane decomposition (256 threads stage 32KB K + 32KB V per tile)
  const int k_sub = lane >> 5;        // K: 2 rows / instr (row stride 512B)
  const int k_g   = lane & 31;
  const int v_sub = lane >> 3;        // V: 8 rows / instr (row stride 128B)
  const int v_g   = lane & 7;

#define STAGE_TILE(TIDX, BUF)                                                        \
  {                                                                                  \
    const unsigned short* kt = kg_base + (size_t)(TIDX) * SBLK * HE;                 \
    const unsigned short* vt = vt_base + (size_t)(TIDX) * SBLK;                      \
    unsigned short* Kb = Kbuf + (BUF) * (SBLK * 256);                                \
    unsigned short* Vb = Vbuf + (BUF) * (256 * SBLK);                                \
    _Pragma("unroll")                                                                \
    for (int i = 0; i < 8; ++i) {                                                    \
      int row = 16 * wid + 2 * i + k_sub;                                            \
      int gs = k_g ^ (row & 7);                                                      \
      gll16(kt + (size_t)row * HE + gs * 8, Kb + (16 * wid + 2 * i) * 256);          \
    }                                                                                \
    _Pragma("unroll")                                                                \
    for (int i = 0; i < 8; ++i) {                                                    \
      int row = 64 * wid + 8 * i + v_sub;                                            \
      int gs = v_g ^ (row & 7);                                                      \
      gll16(vt + (size_t)row * TT + gs * 8, Vb + (64 * wid + 8 * i) * SBLK);         \
    }                                                                                \
  }

  STAGE_TILE(0, 0)
  asm volatile("s_waitcnt vmcnt(0)" ::: "memory");
  __builtin_amdgcn_s_barrier();
  __builtin_amdgcn_sched_barrier(0);

  for (int t = 0; t < 16; ++t) {
    const int cur = t & 1;
    if (t + 1 < 16) STAGE_TILE(t + 1, cur ^ 1)

    const unsigned short* Kb = Kbuf + cur * (SBLK * 256);
    const unsigned short* Vb = Vbuf + cur * (256 * SBLK);
    const int sxor = lo & 7;

#pragma unroll
    for (int ss = 0; ss < 2; ++ss) {
      // ---- QK^T (swapped): S^T[32 s x 64 q], one K-frag read -> 2 MFMA
      f32x16 sacc0, sacc1;
#pragma unroll
      for (int q = 0; q < 16; ++q) { sacc0[q] = 0.f; sacc1[q] = 0.f; }
      const int srow = 32 * ss + lo;
#pragma unroll
      for (int ks = 0; ks < 16; ++ks) {
        int slot = (ks * 2 + hi) ^ sxor;
        short8 kf = *reinterpret_cast<const short8*>(&Kb[srow * 256 + slot * 8]);
        sacc0 = __builtin_amdgcn_mfma_f32_32x32x16_bf16(kf, qf0[ks], sacc0, 0, 0, 0);
        sacc1 = __builtin_amdgcn_mfma_f32_32x32x16_bf16(kf, qf1[ks], sacc1, 0, 0, 0);
      }

      // ---- softmax numerator + pack to PV A-frags (per q-subtile)
      short8 pa00, pa01, pa10, pa11;
      softmax_pack(sacc0, lacc0, pa00, pa01);
      softmax_pack(sacc1, lacc1, pa10, pa11);

      // ---- PV: one V-frag read -> 2 MFMA
#pragma unroll
      for (int et = 0; et < 8; ++et) {
        const int erow = et * 32 + lo;
        {
          int slot = (4 * ss + 0 + hi) ^ sxor;
          short8 vf = *reinterpret_cast<const short8*>(&Vb[erow * SBLK + slot * 8]);
          Oacc0[et] = __builtin_amdgcn_mfma_f32_32x32x16_bf16(pa00, vf, Oacc0[et], 0, 0, 0);
          Oacc1[et] = __builtin_amdgcn_mfma_f32_32x32x16_bf16(pa10, vf, Oacc1[et], 0, 0, 0);
        }
        {
          int slot = (4 * ss + 2 + hi) ^ sxor;
          short8 vf = *reinterpret_cast<const short8*>(&Vb[erow * SBLK + slot * 8]);
          Oacc0[et] = __builtin_amdgcn_mfma_f32_32x32x16_bf16(pa01, vf, Oacc0[et], 0, 0, 0);
          Oacc1[et] = __builtin_amdgcn_mfma_f32_32x32x16_bf16(pa11, vf, Oacc1[et], 0, 0, 0);
        }
      }
    }

    asm volatile("s_waitcnt vmcnt(0)" ::: "memory");
    __builtin_amdgcn_s_barrier();
    __builtin_amdgcn_sched_barrier(0);
  }

  // ---- epilogue: fold hi halves of lacc, redistribute by q-row, store
  lacc0 += __shfl_xor(lacc0, 32);
  lacc1 += __shfl_xor(lacc1, 32);
  if (hi == 0) {
    lpart[wid * 64 + lo] = lacc0;
    lpart[wid * 64 + 32 + lo] = lacc1;
  }
  __syncthreads();
#pragma unroll
  for (int q = 0; q < 16; ++q) {
    int rr = (q & 3) + 8 * (q >> 2) + 4 * hi;
    float inv0 = 1.0f / lpart[wid * 64 + rr];
    float inv1 = 1.0f / lpart[wid * 64 + 32 + rr];
    int tq0 = t0 + 64 * wid + rr;
    int tq1 = tq0 + 32;
#pragma unroll
    for (int et = 0; et < 8; ++et) {
      og[qkbase + (size_t)tq0 * HE + et * 32 + lo] = f2bf(Oacc0[et][q] * inv0);
      og[qkbase + (size_t)tq1 * HE + et * 32 + lo] = f2bf(Oacc1[et][q] * inv1);
    }
  }
#undef STAGE_TILE
}

// ---------------------------------------------------------------------------
// Kernel 3: output projection (MFMA) + bias + residual into out cols 256..511
//   (unchanged from R6)
// ---------------------------------------------------------------------------
#define PSTR 72
__global__ __launch_bounds__(256) void proj_mfma_kernel(const unsigned short* __restrict__ ao,
                                                        const float* __restrict__ Wu,
                                                        const float* __restrict__ bu,
                                                        const float* __restrict__ x,
                                                        float* __restrict__ out) {
  __shared__ unsigned short As[64 * PSTR];
  __shared__ unsigned short Bs[128 * PSTR];
  const int tid = threadIdx.x;
  const int lane = tid & 63;
  const int wid = tid >> 6;
  const int wr = wid >> 1, wc = wid & 1;
  const int lo = lane & 31, hi = lane >> 5;

  // XCD swizzle: xcd = bid&7; 16 m-tiles per XCD, nt inner
  int bid = blockIdx.x;
  int r = bid >> 3;
  int mt = (bid & 7) * 16 + (r & 15);
  int nt = r >> 4;                      // 0..1
  const int m0 = mt * 64;
  const int n0 = nt * 128;

  const int arow = tid >> 2;            // 0..63
  const int ag0 = (tid & 3) * 2;        // granules {ag0, ag0+1}
  const int brow = tid >> 1;            // 0..127
  const int bg0 = (tid & 1) * 4;        // granules bg0..bg0+4

  short8 raA[2];
  float4 raB[8];
  f32x16 acc[2];
#pragma unroll
  for (int a = 0; a < 2; ++a)
#pragma unroll
    for (int q = 0; q < 16; ++q) acc[a][q] = 0.f;

  // prologue load k0=0
#pragma unroll
  for (int j = 0; j < 2; ++j)
    raA[j] = *reinterpret_cast<const short8*>(&ao[(size_t)(m0 + arow) * HE + (ag0 + j) * 8]);
#pragma unroll
  for (int g = 0; g < 4; ++g) {
    raB[2 * g]     = *reinterpret_cast<const float4*>(&Wu[(size_t)(n0 + brow) * HE + (bg0 + g) * 8]);
    raB[2 * g + 1] = *reinterpret_cast<const float4*>(&Wu[(size_t)(n0 + brow) * HE + (bg0 + g) * 8 + 4]);
  }

  for (int t = 0; t < 32; ++t) {
#pragma unroll
    for (int j = 0; j < 2; ++j)
      *reinterpret_cast<short8*>(&As[arow * PSTR + (ag0 + j) * 8]) = raA[j];
#pragma unroll
    for (int g = 0; g < 4; ++g) {
      union { unsigned int u[4]; short8 v; } w;
      w.u[0] = pk_bf16(raB[2 * g].x, raB[2 * g].y);
      w.u[1] = pk_bf16(raB[2 * g].z, raB[2 * g].w);
      w.u[2] = pk_bf16(raB[2 * g + 1].x, raB[2 * g + 1].y);
      w.u[3] = pk_bf16(raB[2 * g + 1].z, raB[2 * g + 1].w);
      *reinterpret_cast<short8*>(&Bs[brow * PSTR + (bg0 + g) * 8]) = w.v;
    }
    asm volatile("s_waitcnt lgkmcnt(0)" ::: "memory");
    __builtin_amdgcn_s_barrier();
    __builtin_amdgcn_sched_barrier(0);

    if (t + 1 < 32) {
      int k0 = (t + 1) * 64;
#pragma unroll
      for (int j = 0; j < 2; ++j)
        raA[j] = *reinterpret_cast<const short8*>(&ao[(size_t)(m0 + arow) * HE + k0 + (ag0 + j) * 8]);
#pragma unroll
      for (int g = 0; g < 4; ++g) {
        raB[2 * g]     = *reinterpret_cast<const float4*>(&Wu[(size_t)(n0 + brow) * HE + k0 + (bg0 + g) * 8]);
        raB[2 * g + 1] = *reinterpret_cast<const float4*>(&Wu[(size_t)(n0 + brow) * HE + k0 + (bg0 + g) * 8 + 4]);
      }
    }

    __builtin_amdgcn_s_setprio(1);
#pragma unroll
    for (int ks = 0; ks < 4; ++ks) {
      short8 af = *reinterpret_cast<const short8*>(&As[(32 * wr + lo) * PSTR + ks * 16 + hi * 8]);
#pragma unroll
      for (int ni = 0; ni < 2; ++ni) {
        short8 bf = *reinterpret_cast<const short8*>(&Bs[(64 * wc + 32 * ni + lo) * PSTR + ks * 16 + hi * 8]);
        acc[ni] = __builtin_amdgcn_mfma_f32_32x32x16_bf16(af, bf, acc[ni], 0, 0, 0);
      }
    }
    __builtin_amdgcn_s_setprio(0);
    __builtin_amdgcn_s_barrier();
    __builtin_amdgcn_sched_barrier(0);
  }

  // epilogue: += x2 + bias, f32 out
#pragma unroll
  for (int ni = 0; ni < 2; ++ni) {
    int n = n0 + 64 * wc + 32 * ni + lo;
    float bias = bu[n];
#pragma unroll
    for (int q = 0; q < 16; ++q) {
      int rr = (q & 3) + 8 * (q >> 2) + 4 * hi;
      int m = m0 + 32 * wr + rr;
      float o = acc[ni][q] + x[(size_t)m * CC + EE + n] + bias;
      out[(size_t)m * CC + EE + n] = o;
    }
  }
}

// ---------------------------------------------------------------------------
extern "C" void kernel_launch(void* const* d_in, const int* in_sizes, int n_in,
                              void* d_out, int out_size, void* d_ws, size_t ws_size,
                              hipStream_t stream) {
  const float* x  = (const float*)d_in[0];
  const float* Wq = (const float*)d_in[1];
  const float* Wk = (const float*)d_in[2];
  const float* Wv = (const float*)d_in[3];
  const float* Wu = (const float*)d_in[4];
  const float* bu = (const float*)d_in[5];
  float* out = (float*)d_out;

  unsigned short* q  = (unsigned short*)d_ws;
  unsigned short* k  = q + (size_t)MM * HE;
  unsigned short* vt = k + (size_t)MM * HE;
  unsigned short* ao = vt + (size_t)MM * HE;

  qkv_fused_kernel<<<dim3(1024), dim3(512), 0, stream>>>(x, Wq, Wk, Wv, q, k, vt, out);

  attn_kernel<<<dim3(256), dim3(256), 0, stream>>>(q, k, vt, ao);

  proj_mfma_kernel<<<dim3(256), dim3(256), 0, stream>>>(ao, Wu, bu, x, out);
}

// Round 8
// 164.808 us; speedup vs baseline: 2.6077x; 2.6077x over previous
//
#include <hip/hip_runtime.h>
#include <hip/hip_bf16.h>

// Problem constants
#define BB 8
#define TT 1024
#define CC 512
#define HH 8
#define EE 256            // head dim (= C/2)
#define MM (BB*TT)        // 8192 rows
#define HE (HH*EE)        // 2048

using short8 = __attribute__((ext_vector_type(8))) short;
using f32x16 = __attribute__((ext_vector_type(16))) float;
using uint2v = __attribute__((ext_vector_type(2))) unsigned int;

__device__ __forceinline__ float bf2f(unsigned short u) {
  union { float f; unsigned int i; } v; v.i = ((unsigned int)u) << 16; return v.f;
}
__device__ __forceinline__ unsigned short f2bf(float f) {
  union { float f; unsigned int i; } v; v.f = f;
  unsigned int r = v.i + 0x7FFFu + ((v.i >> 16) & 1u);  // RNE
  return (unsigned short)(r >> 16);
}
__device__ __forceinline__ unsigned int pk_bf16(float lo, float hi) {
  unsigned int r;
  asm("v_cvt_pk_bf16_f32 %0, %1, %2" : "=v"(r) : "v"(lo), "v"(hi));
  return r;
}
// async global->LDS, 16B per lane; LDS dest = uniform base + lane*16
__device__ __forceinline__ void gll16(const void* g, void* l) {
  __builtin_amdgcn_global_load_lds(
      (const __attribute__((address_space(1))) unsigned int*)g,
      (__attribute__((address_space(3))) unsigned int*)l, 16, 0, 0);
}

// ---------------------------------------------------------------------------
// Kernel 1: FUSED QKV projection (MFMA) + x1 passthrough copy.
//   For w in {q,k,v}:  Cw[m][n] = scale_w * sum_k x[m][k] * Ww[n][k]
//   BM=BN=128, BK=64, 512 thr / 8 waves (2 wr x 4 wc), 4 K-iters, acc[3].
//   A staged once per iter (shared by all 3).  nt==0 blocks also store the
//   x1 tile (f32 regs they already loaded) to out cols 0..255 (copy fusion).
//   q scale folds log2(e) so attn can use exp2 directly.
//   V epilogue: LDS transpose -> vt[(b*8+h)*256+e][t] coalesced stores.
//   Grid 1024 1-D, mt-inner XCD swizzle: 8 m-tiles per XCD share B in L2.
// ---------------------------------------------------------------------------
#define FSTR 72
__global__ __launch_bounds__(512) void qkv_fused_kernel(const float* __restrict__ x,
                                                        const float* __restrict__ Wq,
                                                        const float* __restrict__ Wk,
                                                        const float* __restrict__ Wv,
                                                        unsigned short* __restrict__ outq,
                                                        unsigned short* __restrict__ outk,
                                                        unsigned short* __restrict__ outvt,
                                                        float* __restrict__ out) {
  __shared__ unsigned short smem[4 * 128 * FSTR];   // As, Bq, Bk, Bv  (73728 B)
  unsigned short* As = smem;
  unsigned short* Bs[3] = { smem + 128 * FSTR, smem + 2 * 128 * FSTR, smem + 3 * 128 * FSTR };

  const int tid = threadIdx.x;
  const int lane = tid & 63;
  const int wid = tid >> 6;
  const int wr = wid >> 2, wc = wid & 3;
  const int lo = lane & 31, hi = lane >> 5;

  // XCD swizzle: xcd = bid&7 owns m-tiles [xcd*8, xcd*8+8), mt-inner
  int bid = blockIdx.x;
  int r = bid >> 3;
  int mt = (bid & 7) * 8 + (r & 7);
  int nt = r >> 3;                      // 0..15
  const int m0 = mt * 128;
  const int n0 = nt * 128;

  const float* Wp[3] = { Wq, Wk, Wv };
  const float scl[3] = { 0.25f * 1.44269504089f, 0.25f, 1.0f };

  const int srow = tid >> 2;            // 0..127
  const int sc0 = (tid & 3) * 16;       // f32 col base (16 per thread)

  float4 ra[4], rb[3][4];
  f32x16 acc[3][2];
#pragma unroll
  for (int w = 0; w < 3; ++w)
#pragma unroll
    for (int mi = 0; mi < 2; ++mi)
#pragma unroll
      for (int q = 0; q < 16; ++q) acc[w][mi][q] = 0.f;

  // prologue loads (k0 = 0)
#pragma unroll
  for (int j = 0; j < 4; ++j)
    ra[j] = *reinterpret_cast<const float4*>(&x[(size_t)(m0 + srow) * CC + sc0 + 4 * j]);
#pragma unroll
  for (int w = 0; w < 3; ++w)
#pragma unroll
    for (int j = 0; j < 4; ++j)
      rb[w][j] = *reinterpret_cast<const float4*>(&Wp[w][(size_t)(n0 + srow) * EE + sc0 + 4 * j]);

  for (int t = 0; t < 4; ++t) {
    // cvt + ds_write current regs
    {
      union { unsigned int u[4]; short8 v; } p0, p1;
      p0.u[0] = pk_bf16(ra[0].x, ra[0].y); p0.u[1] = pk_bf16(ra[0].z, ra[0].w);
      p0.u[2] = pk_bf16(ra[1].x, ra[1].y); p0.u[3] = pk_bf16(ra[1].z, ra[1].w);
      p1.u[0] = pk_bf16(ra[2].x, ra[2].y); p1.u[1] = pk_bf16(ra[2].z, ra[2].w);
      p1.u[2] = pk_bf16(ra[3].x, ra[3].y); p1.u[3] = pk_bf16(ra[3].z, ra[3].w);
      *reinterpret_cast<short8*>(&As[srow * FSTR + sc0]) = p0.v;
      *reinterpret_cast<short8*>(&As[srow * FSTR + sc0 + 8]) = p1.v;
#pragma unroll
      for (int w = 0; w < 3; ++w) {
        union { unsigned int u[4]; short8 v; } q0, q1;
        q0.u[0] = pk_bf16(rb[w][0].x, rb[w][0].y); q0.u[1] = pk_bf16(rb[w][0].z, rb[w][0].w);
        q0.u[2] = pk_bf16(rb[w][1].x, rb[w][1].y); q0.u[3] = pk_bf16(rb[w][1].z, rb[w][1].w);
        q1.u[0] = pk_bf16(rb[w][2].x, rb[w][2].y); q1.u[1] = pk_bf16(rb[w][2].z, rb[w][2].w);
        q1.u[2] = pk_bf16(rb[w][3].x, rb[w][3].y); q1.u[3] = pk_bf16(rb[w][3].z, rb[w][3].w);
        *reinterpret_cast<short8*>(&Bs[w][srow * FSTR + sc0]) = q0.v;
        *reinterpret_cast<short8*>(&Bs[w][srow * FSTR + sc0 + 8]) = q1.v;
      }
    }
    // fused x1 copy: nt==0 blocks store the x-tile slice (still in ra)
    if (n0 == 0) {
      int k0 = t * 64;
#pragma unroll
      for (int j = 0; j < 4; ++j)
        *reinterpret_cast<float4*>(&out[(size_t)(m0 + srow) * CC + k0 + sc0 + 4 * j]) = ra[j];
    }
    asm volatile("s_waitcnt lgkmcnt(0)" ::: "memory");
    __builtin_amdgcn_s_barrier();
    __builtin_amdgcn_sched_barrier(0);

    if (t + 1 < 4) {
      int k0 = (t + 1) * 64;
#pragma unroll
      for (int j = 0; j < 4; ++j)
        ra[j] = *reinterpret_cast<const float4*>(&x[(size_t)(m0 + srow) * CC + k0 + sc0 + 4 * j]);
#pragma unroll
      for (int w = 0; w < 3; ++w)
#pragma unroll
        for (int j = 0; j < 4; ++j)
          rb[w][j] = *reinterpret_cast<const float4*>(&Wp[w][(size_t)(n0 + srow) * EE + k0 + sc0 + 4 * j]);
    }

    __builtin_amdgcn_s_setprio(1);
#pragma unroll
    for (int ks = 0; ks < 4; ++ks) {
      short8 af[2];
#pragma unroll
      for (int mi = 0; mi < 2; ++mi)
        af[mi] = *reinterpret_cast<const short8*>(&As[(64 * wr + 32 * mi + lo) * FSTR + ks * 16 + hi * 8]);
#pragma unroll
      for (int w = 0; w < 3; ++w) {
        short8 bf = *reinterpret_cast<const short8*>(&Bs[w][(32 * wc + lo) * FSTR + ks * 16 + hi * 8]);
#pragma unroll
        for (int mi = 0; mi < 2; ++mi)
          acc[w][mi] = __builtin_amdgcn_mfma_f32_32x32x16_bf16(af[mi], bf, acc[w][mi], 0, 0, 0);
      }
    }
    __builtin_amdgcn_s_setprio(0);
    __builtin_amdgcn_s_barrier();
    __builtin_amdgcn_sched_barrier(0);
  }

  // ---- epilogue: q, k direct coalesced stores
#pragma unroll
  for (int w = 0; w < 2; ++w) {
    unsigned short* op = (w == 0) ? outq : outk;
#pragma unroll
    for (int mi = 0; mi < 2; ++mi) {
#pragma unroll
      for (int q = 0; q < 16; ++q) {
        int rr = (q & 3) + 8 * (q >> 2) + 4 * hi;
        int m = m0 + 64 * wr + 32 * mi + rr;
        int n = n0 + 32 * wc + lo;
        op[(size_t)m * HE + n] = f2bf(acc[w][mi][q] * scl[w]);
      }
    }
  }

  // ---- V: LDS transpose then coalesced vt stores
  unsigned short* Tr = smem;            // [128 n][136] m-major rows
  __syncthreads();                      // everyone done with As/Bs
#pragma unroll
  for (int mi = 0; mi < 2; ++mi)
#pragma unroll
    for (int q = 0; q < 16; ++q) {
      int rr = (q & 3) + 8 * (q >> 2) + 4 * hi;
      Tr[(32 * wc + lo) * 136 + 64 * wr + 32 * mi + rr] = f2bf(acc[2][mi][q]);
    }
  __syncthreads();
  {
    const int b = m0 >> 10;
    const int t0m = m0 & 1023;
#pragma unroll
    for (int p = 0; p < 4; ++p) {
      int nr = p * 32 + (tid >> 4);
      int chunk = tid & 15;
      int n = n0 + nr;
      size_t drow = ((size_t)b * 8 + (n >> 8)) * 256 + (n & 255);
      *reinterpret_cast<short8*>(&outvt[drow * TT + t0m + chunk * 8]) =
          *reinterpret_cast<const short8*>(&Tr[nr * 136 + chunk * 8]);
    }
  }
}

// ---------------------------------------------------------------------------
// Kernel 2: pipelined MFMA attention (R6-proven structure, setprio removed).
//   256 thr = 4 waves, each wave owns 32 q-rows (QBLK=128), SBLK=32,
//   32 K/V tiles, no s-split.  K[32][256] + Vt[256][32] double-buffered.
//   global_load_lds staging with XOR-granule pre-swizzle on global source.
//   Main loop: stage(t+1, other buf) -> compute(t) -> vmcnt(0)+barrier.
//   Softmax = exp2 (log2e folded into q scale), P packed in-register via
//   v_cvt_pk_bf16_f32 + permlane32_swap.
// ---------------------------------------------------------------------------
#define SBLK 32
__global__ __launch_bounds__(256, 2) void attn_kernel(const unsigned short* __restrict__ qg,
                                                      const unsigned short* __restrict__ kg,
                                                      const unsigned short* __restrict__ vtg,
                                                      unsigned short* __restrict__ og) {
  __shared__ char smem[66048];
  unsigned short* Kbuf = (unsigned short*)smem;              // 2 x [32][256]
  unsigned short* Vbuf = (unsigned short*)(smem + 32768);    // 2 x [256][32]
  float* lpart = (float*)(smem + 65536);                     // [128]

  const int tid = threadIdx.x;
  const int lane = tid & 63;
  const int wid = tid >> 6;           // 0..3: q-subtile
  const int lo = lane & 31, hi = lane >> 5;

  // XCD-aware bijective swizzle: 8 t-tiles of each (b,h) stay on one XCD
  int logical = (blockIdx.x & 7) * 64 + (blockIdx.x >> 3);
  const int bh = logical >> 3;
  const int t0 = (logical & 7) * 128;
  const int b = bh >> 3, h = bh & 7;
  const size_t qkbase = (size_t)b * TT * HE + (size_t)h * EE;
  const size_t vtbase = (size_t)bh * EE * TT;
  const unsigned short* kg_base = kg + qkbase;
  const unsigned short* vt_base = vtg + vtbase;

  // hoist Q fragments (B-operand): lane holds q-row t0+32*wid+lo
  short8 qf[16];
  {
    const unsigned short* qrow = qg + qkbase + (size_t)(t0 + 32 * wid + lo) * HE + hi * 8;
#pragma unroll
    for (int ks = 0; ks < 16; ++ks)
      qf[ks] = *reinterpret_cast<const short8*>(qrow + ks * 16);
  }

  f32x16 Oacc[8];
#pragma unroll
  for (int et = 0; et < 8; ++et)
#pragma unroll
    for (int q = 0; q < 16; ++q) Oacc[et][q] = 0.f;
  float lacc = 0.f;

  // staging lane decomposition
  const int k_sub = lane >> 5;        // K: 2 rows / instr
  const int k_g   = lane & 31;
  const int v_er  = lane >> 2;        // V: 16 rows / instr
  const int v_g   = lane & 3;
  const int v_gs  = v_g ^ ((lane >> 3) & 3);

#define STAGE_TILE(TIDX, BUF)                                                        \
  {                                                                                  \
    const unsigned short* kt = kg_base + (size_t)(TIDX) * SBLK * HE;                 \
    const unsigned short* vt = vt_base + (size_t)(TIDX) * SBLK;                      \
    unsigned short* Kb = Kbuf + (BUF) * (SBLK * 256);                                \
    unsigned short* Vb = Vbuf + (BUF) * (256 * SBLK);                                \
    _Pragma("unroll")                                                                \
    for (int i = 0; i < 4; ++i) {                                                    \
      int row = 8 * wid + 2 * i + k_sub;                                             \
      int gs = k_g ^ (row & 7);                                                      \
      gll16(kt + (size_t)row * HE + gs * 8, Kb + (8 * wid + 2 * i) * 256);           \
    }                                                                                \
    _Pragma("unroll")                                                                \
    for (int i = 0; i < 4; ++i) {                                                    \
      int row = 64 * wid + 16 * i + v_er;                                            \
      gll16(vt + (size_t)row * TT + v_gs * 8, Vb + (64 * wid + 16 * i) * SBLK);      \
    }                                                                                \
  }

  STAGE_TILE(0, 0)
  asm volatile("s_waitcnt vmcnt(0)" ::: "memory");
  __builtin_amdgcn_s_barrier();
  __builtin_amdgcn_sched_barrier(0);

  for (int t = 0; t < 32; ++t) {
    const int cur = t & 1;
    if (t + 1 < 32) STAGE_TILE(t + 1, cur ^ 1)

    const unsigned short* Kb = Kbuf + cur * (SBLK * 256);
    const unsigned short* Vb = Vbuf + cur * (256 * SBLK);

    // ---- QK^T (swapped): S^T[32 s x 32 q]
    f32x16 sacc;
#pragma unroll
    for (int q = 0; q < 16; ++q) sacc[q] = 0.f;
    const int sxor = lo & 7;
#pragma unroll
    for (int ks = 0; ks < 16; ++ks) {
      int slot = (ks * 2 + hi) ^ sxor;
      short8 kf = *reinterpret_cast<const short8*>(&Kb[lo * 256 + slot * 8]);
      sacc = __builtin_amdgcn_mfma_f32_32x32x16_bf16(kf, qf[ks], sacc, 0, 0, 0);
    }

    // ---- softmax numerator (exp2; log2e pre-folded) + pack to A-frags
    short8 pa[2];
#pragma unroll
    for (int ksl = 0; ksl < 2; ++ksl) {
      float p0 = __builtin_amdgcn_exp2f(sacc[8 * ksl + 0]);
      float p1 = __builtin_amdgcn_exp2f(sacc[8 * ksl + 1]);
      float p2 = __builtin_amdgcn_exp2f(sacc[8 * ksl + 2]);
      float p3 = __builtin_amdgcn_exp2f(sacc[8 * ksl + 3]);
      float p4 = __builtin_amdgcn_exp2f(sacc[8 * ksl + 4]);
      float p5 = __builtin_amdgcn_exp2f(sacc[8 * ksl + 5]);
      float p6 = __builtin_amdgcn_exp2f(sacc[8 * ksl + 6]);
      float p7 = __builtin_amdgcn_exp2f(sacc[8 * ksl + 7]);
      lacc += ((p0 + p1) + (p2 + p3)) + ((p4 + p5) + (p6 + p7));
      unsigned int a1 = pk_bf16(p0, p1), a2 = pk_bf16(p2, p3);
      unsigned int b1 = pk_bf16(p4, p5), b2 = pk_bf16(p6, p7);
      uint2v r1 = __builtin_amdgcn_permlane32_swap(a1, b1, false, false);
      uint2v r2 = __builtin_amdgcn_permlane32_swap(a2, b2, false, false);
      union { unsigned int u[4]; short8 v; } uu;
      uu.u[0] = r1[0]; uu.u[1] = r2[0]; uu.u[2] = r1[1]; uu.u[3] = r2[1];
      pa[ksl] = uu.v;
    }

    // ---- PV: O[32q][256e] += P[32q][32s] * V[32s][256e]
    const int vxor = (lo >> 1) & 3;
#pragma unroll
    for (int et = 0; et < 8; ++et) {
      const int erow = et * 32 + lo;
#pragma unroll
      for (int ksl = 0; ksl < 2; ++ksl) {
        int slot = (2 * ksl + hi) ^ vxor;
        short8 vf = *reinterpret_cast<const short8*>(&Vb[erow * SBLK + slot * 8]);
        Oacc[et] = __builtin_amdgcn_mfma_f32_32x32x16_bf16(pa[ksl], vf, Oacc[et], 0, 0, 0);
      }
    }

    asm volatile("s_waitcnt vmcnt(0)" ::: "memory");
    __builtin_amdgcn_s_barrier();
    __builtin_amdgcn_sched_barrier(0);
  }

  // ---- epilogue: fold hi halves of lacc, redistribute by q-row, store
  lacc += __shfl_xor(lacc, 32);
  if (hi == 0) lpart[wid * 32 + lo] = lacc;
  __syncthreads();
#pragma unroll
  for (int q = 0; q < 16; ++q) {
    int rr = (q & 3) + 8 * (q >> 2) + 4 * hi;
    float inv = 1.0f / lpart[wid * 32 + rr];
    int tq = t0 + 32 * wid + rr;
#pragma unroll
    for (int et = 0; et < 8; ++et)
      og[qkbase + (size_t)tq * HE + et * 32 + lo] = f2bf(Oacc[et][q] * inv);
  }
#undef STAGE_TILE
}

// ---------------------------------------------------------------------------
// Kernel 3: output projection (MFMA) + bias + residual into out cols 256..511
//   A = ao bf16 [8192][2048], B = Wu f32 [256][2048].
//   BM=64, BN=64, BK=64, 256 thr / 4 waves (2 wr x 2 wc), 32 K-iters.
//   Grid 512 1-D -> 2 blocks/CU so per-iter drains overlap across blocks.
//   XCD swizzle: 16 mt x 4 nt per XCD (ao slice ~4MB L2-resident; Wu resident).
// ---------------------------------------------------------------------------
#define PSTR 72
__global__ __launch_bounds__(256) void proj_mfma_kernel(const unsigned short* __restrict__ ao,
                                                        const float* __restrict__ Wu,
                                                        const float* __restrict__ bu,
                                                        const float* __restrict__ x,
                                                        float* __restrict__ out) {
  __shared__ unsigned short As[64 * PSTR];
  __shared__ unsigned short Bs[64 * PSTR];
  const int tid = threadIdx.x;
  const int lane = tid & 63;
  const int wid = tid >> 6;
  const int wr = wid >> 1, wc = wid & 1;
  const int lo = lane & 31, hi = lane >> 5;

  // XCD swizzle: xcd = bid&7; r = bid>>3 in 0..63: mt = xcd*16 + (r&15), nt = r>>4
  int bid = blockIdx.x;
  int r = bid >> 3;
  int mt = (bid & 7) * 16 + (r & 15);   // 0..127
  int nt = r >> 4;                      // 0..3
  const int m0 = mt * 64;
  const int n0 = nt * 64;

  const int arow = tid >> 2;            // 0..63
  const int ag0 = (tid & 3) * 2;        // bf16 granule pair {ag0, ag0+1} of 8
  const int brow = tid >> 2;            // 0..63
  const int bg0 = (tid & 3) * 4;        // float4 index base (4 per thread of 16)

  short8 raA[2];
  float4 raB[4];
  f32x16 acc;
#pragma unroll
  for (int q = 0; q < 16; ++q) acc[q] = 0.f;

  // prologue load k0=0
#pragma unroll
  for (int j = 0; j < 2; ++j)
    raA[j] = *reinterpret_cast<const short8*>(&ao[(size_t)(m0 + arow) * HE + (ag0 + j) * 8]);
#pragma unroll
  for (int g = 0; g < 4; ++g)
    raB[g] = *reinterpret_cast<const float4*>(&Wu[(size_t)(n0 + brow) * HE + (bg0 + g) * 4]);

  for (int t = 0; t < 32; ++t) {
#pragma unroll
    for (int j = 0; j < 2; ++j)
      *reinterpret_cast<short8*>(&As[arow * PSTR + (ag0 + j) * 8]) = raA[j];
    {
      union { unsigned int u[4]; short8 v; } w0, w1;
      w0.u[0] = pk_bf16(raB[0].x, raB[0].y); w0.u[1] = pk_bf16(raB[0].z, raB[0].w);
      w0.u[2] = pk_bf16(raB[1].x, raB[1].y); w0.u[3] = pk_bf16(raB[1].z, raB[1].w);
      w1.u[0] = pk_bf16(raB[2].x, raB[2].y); w1.u[1] = pk_bf16(raB[2].z, raB[2].w);
      w1.u[2] = pk_bf16(raB[3].x, raB[3].y); w1.u[3] = pk_bf16(raB[3].z, raB[3].w);
      *reinterpret_cast<short8*>(&Bs[brow * PSTR + ag0 * 8]) = w0.v;
      *reinterpret_cast<short8*>(&Bs[brow * PSTR + (ag0 + 1) * 8]) = w1.v;
    }
    asm volatile("s_waitcnt lgkmcnt(0)" ::: "memory");
    __builtin_amdgcn_s_barrier();
    __builtin_amdgcn_sched_barrier(0);

    if (t + 1 < 32) {
      int k0 = (t + 1) * 64;
#pragma unroll
      for (int j = 0; j < 2; ++j)
        raA[j] = *reinterpret_cast<const short8*>(&ao[(size_t)(m0 + arow) * HE + k0 + (ag0 + j) * 8]);
#pragma unroll
      for (int g = 0; g < 4; ++g)
        raB[g] = *reinterpret_cast<const float4*>(&Wu[(size_t)(n0 + brow) * HE + k0 + (bg0 + g) * 4]);
    }

    __builtin_amdgcn_s_setprio(1);
#pragma unroll
    for (int ks = 0; ks < 4; ++ks) {
      short8 af = *reinterpret_cast<const short8*>(&As[(32 * wr + lo) * PSTR + ks * 16 + hi * 8]);
      short8 bf = *reinterpret_cast<const short8*>(&Bs[(32 * wc + lo) * PSTR + ks * 16 + hi * 8]);
      acc = __builtin_amdgcn_mfma_f32_32x32x16_bf16(af, bf, acc, 0, 0, 0);
    }
    __builtin_amdgcn_s_setprio(0);
    __builtin_amdgcn_s_barrier();
    __builtin_amdgcn_sched_barrier(0);
  }

  // epilogue: += x2 + bias, f32 out
  {
    int n = n0 + 32 * wc + lo;
    float bias = bu[n];
#pragma unroll
    for (int q = 0; q < 16; ++q) {
      int rr = (q & 3) + 8 * (q >> 2) + 4 * hi;
      int m = m0 + 32 * wr + rr;
      float o = acc[q] + x[(size_t)m * CC + EE + n] + bias;
      out[(size_t)m * CC + EE + n] = o;
    }
  }
}

// ---------------------------------------------------------------------------
extern "C" void kernel_launch(void* const* d_in, const int* in_sizes, int n_in,
                              void* d_out, int out_size, void* d_ws, size_t ws_size,
                              hipStream_t stream) {
  const float* x  = (const float*)d_in[0];
  const float* Wq = (const float*)d_in[1];
  const float* Wk = (const float*)d_in[2];
  const float* Wv = (const float*)d_in[3];
  const float* Wu = (const float*)d_in[4];
  const float* bu = (const float*)d_in[5];
  float* out = (float*)d_out;

  unsigned short* q  = (unsigned short*)d_ws;
  unsigned short* k  = q + (size_t)MM * HE;
  unsigned short* vt = k + (size_t)MM * HE;
  unsigned short* ao = vt + (size_t)MM * HE;

  qkv_fused_kernel<<<dim3(1024), dim3(512), 0, stream>>>(x, Wq, Wk, Wv, q, k, vt, out);

  attn_kernel<<<dim3(512), dim3(256), 0, stream>>>(q, k, vt, ao);

  proj_mfma_kernel<<<dim3(512), dim3(256), 0, stream>>>(ao, Wu, bu, x, out);
}

// Round 9
// 154.475 us; speedup vs baseline: 2.7822x; 1.0669x over previous
//
#include <hip/hip_runtime.h>
#include <hip/hip_bf16.h>

// Problem constants
#define BB 8
#define TT 1024
#define CC 512
#define HH 8
#define EE 256            // head dim (= C/2)
#define MM (BB*TT)        // 8192 rows
#define HE (HH*EE)        // 2048

using short8 = __attribute__((ext_vector_type(8))) short;
using f32x16 = __attribute__((ext_vector_type(16))) float;
using uint2v = __attribute__((ext_vector_type(2))) unsigned int;

__device__ __forceinline__ unsigned short f2bf(float f) {
  union { float f; unsigned int i; } v; v.f = f;
  unsigned int r = v.i + 0x7FFFu + ((v.i >> 16) & 1u);  // RNE
  return (unsigned short)(r >> 16);
}
__device__ __forceinline__ unsigned int pk_bf16(float lo, float hi) {
  unsigned int r;
  asm("v_cvt_pk_bf16_f32 %0, %1, %2" : "=v"(r) : "v"(lo), "v"(hi));
  return r;
}
// async global->LDS, 16B per lane; LDS dest = uniform base + lane*16
__device__ __forceinline__ void gll16(const void* g, void* l) {
  __builtin_amdgcn_global_load_lds(
      (const __attribute__((address_space(1))) unsigned int*)g,
      (__attribute__((address_space(3))) unsigned int*)l, 16, 0, 0);
}

// ---------------------------------------------------------------------------
// Kernel 0: prep — bf16 conversions + fragment-swizzled weights + x1 copy.
//   part 1 (t < 262144): xb[m][e] = bf16(x[m][e]) for e<256; out[m][0..255] = x1.
//   part 2: Wf frag layout: slot ((w*64+ng)*16+ks)*64+lane holds 8 bf16 =
//           scale_w * W_w[ng*32 + (lane&31)][ks*16 + (lane>>5)*8 .. +8].
//   (q scale folds log2(e) so attn uses exp2 directly.)
// ---------------------------------------------------------------------------
__global__ __launch_bounds__(256) void prep_kernel(const float* __restrict__ x,
                                                   const float* __restrict__ Wq,
                                                   const float* __restrict__ Wk,
                                                   const float* __restrict__ Wv,
                                                   unsigned short* __restrict__ xb,
                                                   unsigned short* __restrict__ wf,
                                                   float* __restrict__ out) {
  int t = blockIdx.x * 256 + threadIdx.x;
  if (t < 262144) {
    // x1 -> xb (bf16) + x1 -> out (f32)
    int m = t >> 5;
    int c8 = (t & 31) * 8;
    float4 a = *reinterpret_cast<const float4*>(&x[(size_t)m * CC + c8]);
    float4 b = *reinterpret_cast<const float4*>(&x[(size_t)m * CC + c8 + 4]);
    union { unsigned int u[4]; short8 v; } o;
    o.u[0] = pk_bf16(a.x, a.y); o.u[1] = pk_bf16(a.z, a.w);
    o.u[2] = pk_bf16(b.x, b.y); o.u[3] = pk_bf16(b.z, b.w);
    *reinterpret_cast<short8*>(&xb[(size_t)m * 256 + c8]) = o.v;
    *reinterpret_cast<float4*>(&out[(size_t)m * CC + c8]) = a;
    *reinterpret_cast<float4*>(&out[(size_t)m * CC + c8 + 4]) = b;
  } else {
    int t2 = t - 262144;              // [0, 196608)
    int lane = t2 & 63;
    int rest = t2 >> 6;               // [0, 3072)
    int ks = rest & 15;
    int ng = (rest >> 4) & 63;
    int w = rest >> 10;               // 0..2
    const float* Wp = (w == 0) ? Wq : (w == 1) ? Wk : Wv;
    const float scl = (w == 0) ? 0.25f * 1.44269504089f : (w == 1) ? 0.25f : 1.0f;
    int n = ng * 32 + (lane & 31);
    int e0 = ks * 16 + (lane >> 5) * 8;
    float4 a = *reinterpret_cast<const float4*>(&Wp[(size_t)n * EE + e0]);
    float4 b = *reinterpret_cast<const float4*>(&Wp[(size_t)n * EE + e0 + 4]);
    union { unsigned int u[4]; short8 v; } o;
    o.u[0] = pk_bf16(a.x * scl, a.y * scl); o.u[1] = pk_bf16(a.z * scl, a.w * scl);
    o.u[2] = pk_bf16(b.x * scl, b.y * scl); o.u[3] = pk_bf16(b.z * scl, b.w * scl);
    *reinterpret_cast<short8*>(&wf[(size_t)t2 * 8]) = o.v;
  }
}

// ---------------------------------------------------------------------------
// Kernel 1: qkv_static — barrier-free fragment-direct QKV GEMM.
//   BM=64, BN=128, K=256 staged ONCE.  256 thr / 4 waves (wc 0..3).
//   A-tile [64][256] bf16 via gll16 + row&7 XOR granule swizzle (32 KB LDS).
//   ONE barrier; then ks-loop with NO barriers: af from LDS (2 reads),
//   bf[3] streamed from global Wf (coalesced 1KB/wave, L2-resident),
//   6 MFMAs.  Epilogue: q/k direct; V via LDS transpose (aliases A buffer).
//   Grid 2048 1-D, mt-inner XCD swizzle (A slice + Wf stay in per-XCD L2).
// ---------------------------------------------------------------------------
__global__ __launch_bounds__(256) void qkv_static_kernel(const unsigned short* __restrict__ xb,
                                                         const unsigned short* __restrict__ wf,
                                                         unsigned short* __restrict__ outq,
                                                         unsigned short* __restrict__ outk,
                                                         unsigned short* __restrict__ outvt) {
  __shared__ unsigned short Ab[64 * 256];      // 32 KB; reused as Tr[128][72] later

  const int tid = threadIdx.x;
  const int lane = tid & 63;
  const int wid = tid >> 6;           // 0..3
  const int wc = wid;                 // n 32-col group
  const int lo = lane & 31, hi = lane >> 5;

  // XCD swizzle: xcd = bid&7 owns mt [xcd*16, xcd*16+16), mt-inner
  int bid = blockIdx.x;
  int r = bid >> 3;                   // [0, 256)
  int mt = (bid & 7) * 16 + (r & 15); // 0..127
  int nt = r >> 4;                    // 0..15
  const int m0 = mt * 64;
  const int n0 = nt * 128;

  // ---- stage A once: 64 rows x 512 B, wave wid stages rows [16wid,16wid+16)
  {
    const int a_sub = lane >> 5;
    const int a_g = lane & 31;
#pragma unroll
    for (int i = 0; i < 8; ++i) {
      int row = 16 * wid + 2 * i + a_sub;
      int gs = a_g ^ (row & 7);
      gll16(xb + (size_t)(m0 + row) * 256 + gs * 8, Ab + (16 * wid + 2 * i) * 256);
    }
  }
  asm volatile("s_waitcnt vmcnt(0)" ::: "memory");
  __builtin_amdgcn_s_barrier();

  // ---- compute: no barriers in this loop
  f32x16 acc[3][2];
#pragma unroll
  for (int w = 0; w < 3; ++w)
#pragma unroll
    for (int mi = 0; mi < 2; ++mi)
#pragma unroll
      for (int q = 0; q < 16; ++q) acc[w][mi][q] = 0.f;

  const int ng = nt * 4 + wc;
  const short8* wfp = reinterpret_cast<const short8*>(wf);
  const int sxor = lo & 7;

#pragma unroll
  for (int ks = 0; ks < 16; ++ks) {
    short8 bf[3];
#pragma unroll
    for (int w = 0; w < 3; ++w)
      bf[w] = wfp[(size_t)((w * 64 + ng) * 16 + ks) * 64 + lane];
    short8 af[2];
#pragma unroll
    for (int mi = 0; mi < 2; ++mi) {
      int row = 32 * mi + lo;
      int slot = (ks * 2 + hi) ^ sxor;
      af[mi] = *reinterpret_cast<const short8*>(&Ab[row * 256 + slot * 8]);
    }
#pragma unroll
    for (int w = 0; w < 3; ++w)
#pragma unroll
      for (int mi = 0; mi < 2; ++mi)
        acc[w][mi] = __builtin_amdgcn_mfma_f32_32x32x16_bf16(af[mi], bf[w], acc[w][mi], 0, 0, 0);
  }

  // ---- epilogue: q, k direct coalesced stores (scales pre-folded in Wf)
#pragma unroll
  for (int w = 0; w < 2; ++w) {
    unsigned short* op = (w == 0) ? outq : outk;
#pragma unroll
    for (int mi = 0; mi < 2; ++mi) {
#pragma unroll
      for (int q = 0; q < 16; ++q) {
        int rr = (q & 3) + 8 * (q >> 2) + 4 * hi;
        int m = m0 + 32 * mi + rr;
        int n = n0 + 32 * wc + lo;
        op[(size_t)m * HE + n] = f2bf(acc[w][mi][q]);
      }
    }
  }

  // ---- V: LDS transpose (alias A buffer) then coalesced vt stores
  unsigned short* Tr = Ab;            // [128 n][72]: 18.4 KB <= 32 KB
  __syncthreads();                    // A reads done
#pragma unroll
  for (int mi = 0; mi < 2; ++mi)
#pragma unroll
    for (int q = 0; q < 16; ++q) {
      int rr = (q & 3) + 8 * (q >> 2) + 4 * hi;
      Tr[(32 * wc + lo) * 72 + 32 * mi + rr] = f2bf(acc[2][mi][q]);
    }
  __syncthreads();
  {
    const int b = m0 >> 10;
    const int t0m = m0 & 1023;
#pragma unroll
    for (int p = 0; p < 4; ++p) {
      int nr = p * 32 + (tid >> 3);   // 0..127
      int chunk = tid & 7;            // 8 chunks x 8 = 64 m
      int n = n0 + nr;
      size_t drow = ((size_t)b * 8 + (n >> 8)) * 256 + (n & 255);
      *reinterpret_cast<short8*>(&outvt[drow * TT + t0m + chunk * 8]) =
          *reinterpret_cast<const short8*>(&Tr[nr * 72 + chunk * 8]);
    }
  }
}

// ---------------------------------------------------------------------------
// Kernel 2: pipelined MFMA attention (R8-proven, unchanged).
// ---------------------------------------------------------------------------
#define SBLK 32
__global__ __launch_bounds__(256, 2) void attn_kernel(const unsigned short* __restrict__ qg,
                                                      const unsigned short* __restrict__ kg,
                                                      const unsigned short* __restrict__ vtg,
                                                      unsigned short* __restrict__ og) {
  __shared__ char smem[66048];
  unsigned short* Kbuf = (unsigned short*)smem;              // 2 x [32][256]
  unsigned short* Vbuf = (unsigned short*)(smem + 32768);    // 2 x [256][32]
  float* lpart = (float*)(smem + 65536);                     // [128]

  const int tid = threadIdx.x;
  const int lane = tid & 63;
  const int wid = tid >> 6;           // 0..3: q-subtile
  const int lo = lane & 31, hi = lane >> 5;

  // XCD-aware bijective swizzle: 8 t-tiles of each (b,h) stay on one XCD
  int logical = (blockIdx.x & 7) * 64 + (blockIdx.x >> 3);
  const int bh = logical >> 3;
  const int t0 = (logical & 7) * 128;
  const int b = bh >> 3, h = bh & 7;
  const size_t qkbase = (size_t)b * TT * HE + (size_t)h * EE;
  const size_t vtbase = (size_t)bh * EE * TT;
  const unsigned short* kg_base = kg + qkbase;
  const unsigned short* vt_base = vtg + vtbase;

  // hoist Q fragments (B-operand): lane holds q-row t0+32*wid+lo
  short8 qf[16];
  {
    const unsigned short* qrow = qg + qkbase + (size_t)(t0 + 32 * wid + lo) * HE + hi * 8;
#pragma unroll
    for (int ks = 0; ks < 16; ++ks)
      qf[ks] = *reinterpret_cast<const short8*>(qrow + ks * 16);
  }

  f32x16 Oacc[8];
#pragma unroll
  for (int et = 0; et < 8; ++et)
#pragma unroll
    for (int q = 0; q < 16; ++q) Oacc[et][q] = 0.f;
  float lacc = 0.f;

  // staging lane decomposition
  const int k_sub = lane >> 5;        // K: 2 rows / instr
  const int k_g   = lane & 31;
  const int v_er  = lane >> 2;        // V: 16 rows / instr
  const int v_g   = lane & 3;
  const int v_gs  = v_g ^ ((lane >> 3) & 3);

#define STAGE_TILE(TIDX, BUF)                                                        \
  {                                                                                  \
    const unsigned short* kt = kg_base + (size_t)(TIDX) * SBLK * HE;                 \
    const unsigned short* vt = vt_base + (size_t)(TIDX) * SBLK;                      \
    unsigned short* Kb = Kbuf + (BUF) * (SBLK * 256);                                \
    unsigned short* Vb = Vbuf + (BUF) * (256 * SBLK);                                \
    _Pragma("unroll")                                                                \
    for (int i = 0; i < 4; ++i) {                                                    \
      int row = 8 * wid + 2 * i + k_sub;                                             \
      int gs = k_g ^ (row & 7);                                                      \
      gll16(kt + (size_t)row * HE + gs * 8, Kb + (8 * wid + 2 * i) * 256);           \
    }                                                                                \
    _Pragma("unroll")                                                                \
    for (int i = 0; i < 4; ++i) {                                                    \
      int row = 64 * wid + 16 * i + v_er;                                            \
      gll16(vt + (size_t)row * TT + v_gs * 8, Vb + (64 * wid + 16 * i) * SBLK);      \
    }                                                                                \
  }

  STAGE_TILE(0, 0)
  asm volatile("s_waitcnt vmcnt(0)" ::: "memory");
  __builtin_amdgcn_s_barrier();
  __builtin_amdgcn_sched_barrier(0);

  for (int t = 0; t < 32; ++t) {
    const int cur = t & 1;
    if (t + 1 < 32) STAGE_TILE(t + 1, cur ^ 1)

    const unsigned short* Kb = Kbuf + cur * (SBLK * 256);
    const unsigned short* Vb = Vbuf + cur * (256 * SBLK);

    // ---- QK^T (swapped): S^T[32 s x 32 q]
    f32x16 sacc;
#pragma unroll
    for (int q = 0; q < 16; ++q) sacc[q] = 0.f;
    const int sxor = lo & 7;
#pragma unroll
    for (int ks = 0; ks < 16; ++ks) {
      int slot = (ks * 2 + hi) ^ sxor;
      short8 kf = *reinterpret_cast<const short8*>(&Kb[lo * 256 + slot * 8]);
      sacc = __builtin_amdgcn_mfma_f32_32x32x16_bf16(kf, qf[ks], sacc, 0, 0, 0);
    }

    // ---- softmax numerator (exp2; log2e pre-folded) + pack to A-frags
    short8 pa[2];
#pragma unroll
    for (int ksl = 0; ksl < 2; ++ksl) {
      float p0 = __builtin_amdgcn_exp2f(sacc[8 * ksl + 0]);
      float p1 = __builtin_amdgcn_exp2f(sacc[8 * ksl + 1]);
      float p2 = __builtin_amdgcn_exp2f(sacc[8 * ksl + 2]);
      float p3 = __builtin_amdgcn_exp2f(sacc[8 * ksl + 3]);
      float p4 = __builtin_amdgcn_exp2f(sacc[8 * ksl + 4]);
      float p5 = __builtin_amdgcn_exp2f(sacc[8 * ksl + 5]);
      float p6 = __builtin_amdgcn_exp2f(sacc[8 * ksl + 6]);
      float p7 = __builtin_amdgcn_exp2f(sacc[8 * ksl + 7]);
      lacc += ((p0 + p1) + (p2 + p3)) + ((p4 + p5) + (p6 + p7));
      unsigned int a1 = pk_bf16(p0, p1), a2 = pk_bf16(p2, p3);
      unsigned int b1 = pk_bf16(p4, p5), b2 = pk_bf16(p6, p7);
      uint2v r1 = __builtin_amdgcn_permlane32_swap(a1, b1, false, false);
      uint2v r2 = __builtin_amdgcn_permlane32_swap(a2, b2, false, false);
      union { unsigned int u[4]; short8 v; } uu;
      uu.u[0] = r1[0]; uu.u[1] = r2[0]; uu.u[2] = r1[1]; uu.u[3] = r2[1];
      pa[ksl] = uu.v;
    }

    // ---- PV: O[32q][256e] += P[32q][32s] * V[32s][256e]
    const int vxor = (lo >> 1) & 3;
#pragma unroll
    for (int et = 0; et < 8; ++et) {
      const int erow = et * 32 + lo;
#pragma unroll
      for (int ksl = 0; ksl < 2; ++ksl) {
        int slot = (2 * ksl + hi) ^ vxor;
        short8 vf = *reinterpret_cast<const short8*>(&Vb[erow * SBLK + slot * 8]);
        Oacc[et] = __builtin_amdgcn_mfma_f32_32x32x16_bf16(pa[ksl], vf, Oacc[et], 0, 0, 0);
      }
    }

    asm volatile("s_waitcnt vmcnt(0)" ::: "memory");
    __builtin_amdgcn_s_barrier();
    __builtin_amdgcn_sched_barrier(0);
  }

  // ---- epilogue: fold hi halves of lacc, redistribute by q-row, store
  lacc += __shfl_xor(lacc, 32);
  if (hi == 0) lpart[wid * 32 + lo] = lacc;
  __syncthreads();
#pragma unroll
  for (int q = 0; q < 16; ++q) {
    int rr = (q & 3) + 8 * (q >> 2) + 4 * hi;
    float inv = 1.0f / lpart[wid * 32 + rr];
    int tq = t0 + 32 * wid + rr;
#pragma unroll
    for (int et = 0; et < 8; ++et)
      og[qkbase + (size_t)tq * HE + et * 32 + lo] = f2bf(Oacc[et][q] * inv);
  }
#undef STAGE_TILE
}

// ---------------------------------------------------------------------------
// Kernel 3: output projection (MFMA) + bias + residual (R8-proven, unchanged).
// ---------------------------------------------------------------------------
#define PSTR 72
__global__ __launch_bounds__(256) void proj_mfma_kernel(const unsigned short* __restrict__ ao,
                                                        const float* __restrict__ Wu,
                                                        const float* __restrict__ bu,
                                                        const float* __restrict__ x,
                                                        float* __restrict__ out) {
  __shared__ unsigned short As[64 * PSTR];
  __shared__ unsigned short Bs[64 * PSTR];
  const int tid = threadIdx.x;
  const int lane = tid & 63;
  const int wid = tid >> 6;
  const int wr = wid >> 1, wc = wid & 1;
  const int lo = lane & 31, hi = lane >> 5;

  // XCD swizzle: xcd = bid&7; r = bid>>3 in 0..63: mt = xcd*16 + (r&15), nt = r>>4
  int bid = blockIdx.x;
  int r = bid >> 3;
  int mt = (bid & 7) * 16 + (r & 15);   // 0..127
  int nt = r >> 4;                      // 0..3
  const int m0 = mt * 64;
  const int n0 = nt * 64;

  const int arow = tid >> 2;            // 0..63
  const int ag0 = (tid & 3) * 2;        // bf16 granule pair {ag0, ag0+1} of 8
  const int brow = tid >> 2;            // 0..63
  const int bg0 = (tid & 3) * 4;        // float4 index base (4 per thread of 16)

  short8 raA[2];
  float4 raB[4];
  f32x16 acc;
#pragma unroll
  for (int q = 0; q < 16; ++q) acc[q] = 0.f;

  // prologue load k0=0
#pragma unroll
  for (int j = 0; j < 2; ++j)
    raA[j] = *reinterpret_cast<const short8*>(&ao[(size_t)(m0 + arow) * HE + (ag0 + j) * 8]);
#pragma unroll
  for (int g = 0; g < 4; ++g)
    raB[g] = *reinterpret_cast<const float4*>(&Wu[(size_t)(n0 + brow) * HE + (bg0 + g) * 4]);

  for (int t = 0; t < 32; ++t) {
#pragma unroll
    for (int j = 0; j < 2; ++j)
      *reinterpret_cast<short8*>(&As[arow * PSTR + (ag0 + j) * 8]) = raA[j];
    {
      union { unsigned int u[4]; short8 v; } w0, w1;
      w0.u[0] = pk_bf16(raB[0].x, raB[0].y); w0.u[1] = pk_bf16(raB[0].z, raB[0].w);
      w0.u[2] = pk_bf16(raB[1].x, raB[1].y); w0.u[3] = pk_bf16(raB[1].z, raB[1].w);
      w1.u[0] = pk_bf16(raB[2].x, raB[2].y); w1.u[1] = pk_bf16(raB[2].z, raB[2].w);
      w1.u[2] = pk_bf16(raB[3].x, raB[3].y); w1.u[3] = pk_bf16(raB[3].z, raB[3].w);
      *reinterpret_cast<short8*>(&Bs[brow * PSTR + ag0 * 8]) = w0.v;
      *reinterpret_cast<short8*>(&Bs[brow * PSTR + (ag0 + 1) * 8]) = w1.v;
    }
    asm volatile("s_waitcnt lgkmcnt(0)" ::: "memory");
    __builtin_amdgcn_s_barrier();
    __builtin_amdgcn_sched_barrier(0);

    if (t + 1 < 32) {
      int k0 = (t + 1) * 64;
#pragma unroll
      for (int j = 0; j < 2; ++j)
        raA[j] = *reinterpret_cast<const short8*>(&ao[(size_t)(m0 + arow) * HE + k0 + (ag0 + j) * 8]);
#pragma unroll
      for (int g = 0; g < 4; ++g)
        raB[g] = *reinterpret_cast<const float4*>(&Wu[(size_t)(n0 + brow) * HE + k0 + (bg0 + g) * 4]);
    }

    __builtin_amdgcn_s_setprio(1);
#pragma unroll
    for (int ks = 0; ks < 4; ++ks) {
      short8 af = *reinterpret_cast<const short8*>(&As[(32 * wr + lo) * PSTR + ks * 16 + hi * 8]);
      short8 bf = *reinterpret_cast<const short8*>(&Bs[(32 * wc + lo) * PSTR + ks * 16 + hi * 8]);
      acc = __builtin_amdgcn_mfma_f32_32x32x16_bf16(af, bf, acc, 0, 0, 0);
    }
    __builtin_amdgcn_s_setprio(0);
    __builtin_amdgcn_s_barrier();
    __builtin_amdgcn_sched_barrier(0);
  }

  // epilogue: += x2 + bias, f32 out
  {
    int n = n0 + 32 * wc + lo;
    float bias = bu[n];
#pragma unroll
    for (int q = 0; q < 16; ++q) {
      int rr = (q & 3) + 8 * (q >> 2) + 4 * hi;
      int m = m0 + 32 * wr + rr;
      float o = acc[q] + x[(size_t)m * CC + EE + n] + bias;
      out[(size_t)m * CC + EE + n] = o;
    }
  }
}

// ---------------------------------------------------------------------------
extern "C" void kernel_launch(void* const* d_in, const int* in_sizes, int n_in,
                              void* d_out, int out_size, void* d_ws, size_t ws_size,
                              hipStream_t stream) {
  const float* x  = (const float*)d_in[0];
  const float* Wq = (const float*)d_in[1];
  const float* Wk = (const float*)d_in[2];
  const float* Wv = (const float*)d_in[3];
  const float* Wu = (const float*)d_in[4];
  const float* bu = (const float*)d_in[5];
  float* out = (float*)d_out;

  // ws layout (128 MB):
  //   q  [8192][2048] bf16 @ 0        (32 MB)
  //   k  [8192][2048] bf16 @ 16M u16  (32 MB)
  //   vt [64][256][1024] bf16 @ 32M   (32 MB)
  //   ao [8192][2048] bf16 @ 48M      (32 MB)  -- written by attn AFTER
  //   xb (4 MB) + wf (3 MB) alias ao  -- dead once qkv_static completes
  unsigned short* q  = (unsigned short*)d_ws;
  unsigned short* k  = q + (size_t)MM * HE;
  unsigned short* vt = k + (size_t)MM * HE;
  unsigned short* ao = vt + (size_t)MM * HE;
  unsigned short* xb = ao;                       // [8192][256] bf16 (4 MB)
  unsigned short* wfb = xb + (size_t)MM * EE;    // frag weights (3 MB)

  prep_kernel<<<dim3(1792), dim3(256), 0, stream>>>(x, Wq, Wk, Wv, xb, wfb, out);

  qkv_static_kernel<<<dim3(2048), dim3(256), 0, stream>>>(xb, wfb, q, k, vt);

  attn_kernel<<<dim3(512), dim3(256), 0, stream>>>(q, k, vt, ao);

  proj_mfma_kernel<<<dim3(512), dim3(256), 0, stream>>>(ao, Wu, bu, x, out);
}